// Round 11
// baseline (386.244 us; speedup 1.0000x reference)
//
#include <hip/hip_runtime.h>
#include <math.h>
#include <float.h>

// VQ-VAE quantizer, round 11: MEASUREMENT ROUND.
// Identical pipeline to round 10, but vq_main and vq_fin bodies each run
// 12x inside their dispatch (rep loop, barrier + memory clobber per rep,
// idempotent stores). Purpose: each becomes a >43us dispatch that must show
// in rocprof top-5 with full counters (fills no longer mask them).
// Per-rep cost = dispatch_dur / 12. Work per rep is byte-identical to R10.

typedef __attribute__((ext_vector_type(8))) _Float16 f16x8;
typedef __attribute__((ext_vector_type(16))) float f32x16;

typedef __attribute__((address_space(1))) const void gas_t;
typedef __attribute__((address_space(3))) void las_t;
__device__ __forceinline__ void glds16(const void* g, void* l) {
  __builtin_amdgcn_global_load_lds((gas_t*)g, (las_t*)l, 16, 0, 0);
}

#define NREP 12

// ---- prep: emb f32 -> eh fp16 [1024][128] + eh2 = -0.5*|e|^2 (f32) ----
__global__ __launch_bounds__(256)
void vq_prep(const float* __restrict__ emb, _Float16* __restrict__ ehg,
             float* __restrict__ eh2g) {
  const int tid = threadIdx.x;
  const int r = blockIdx.x * 16 + (tid >> 4);
  const int seg = tid & 15;
  const float* row = emb + (size_t)r * 128 + seg * 8;
  float4 f0 = *(const float4*)&row[0];
  float4 f1 = *(const float4*)&row[4];
  float fv[8] = {f0.x, f0.y, f0.z, f0.w, f1.x, f1.y, f1.z, f1.w};
  f16x8 H;
  float ssq = 0.f;
#pragma unroll
  for (int j = 0; j < 8; ++j) {
    float f = fv[j];
    ssq = fmaf(f, f, ssq);
    H[j] = (_Float16)f;
  }
  *(f16x8*)(ehg + (size_t)r * 128 + seg * 8) = H;
#pragma unroll
  for (int off = 1; off < 16; off <<= 1) ssq += __shfl_xor(ssq, off, 64);
  if (seg == 0) eh2g[r] = -0.5f * ssq;
}

// ---- prepx: x [16,1,128,2048] f32 -> xt32 [32768][128] f32 + xth fp16 ----
__global__ __launch_bounds__(256)
void vq_prepx(const float* __restrict__ x, float* __restrict__ xt32,
              _Float16* __restrict__ xth) {
  __shared__ float xs[128 * 132];
  const int tid = threadIdx.x;
  const int b = blockIdx.x >> 4;
  const int tt0 = (blockIdx.x & 15) << 7;
  const float* xp = x + (size_t)b * 262144 + tt0;
  for (int i = tid * 4; i < 16384; i += 1024) {
    int dd = i >> 7, tt = i & 127;
    *(float4*)&xs[dd * 132 + tt] = *(const float4*)&xp[(size_t)dd * 2048 + tt];
  }
  __syncthreads();
  const int t = tid >> 1, half = tid & 1;
  const size_t n = (size_t)b * 2048 + tt0 + t;
  float* r32 = xt32 + n * 128 + half * 64;
  _Float16* r16 = xth + n * 128 + half * 64;
#pragma unroll
  for (int j4 = 0; j4 < 16; ++j4) {
    float4 v;
    v.x = xs[(half * 64 + j4 * 4 + 0) * 132 + t];
    v.y = xs[(half * 64 + j4 * 4 + 1) * 132 + t];
    v.z = xs[(half * 64 + j4 * 4 + 2) * 132 + t];
    v.w = xs[(half * 64 + j4 * 4 + 3) * 132 + t];
    *(float4*)(r32 + j4 * 4) = v;
  }
#pragma unroll
  for (int j8 = 0; j8 < 8; ++j8) {
    f16x8 H;
#pragma unroll
    for (int m = 0; m < 8; ++m)
      H[m] = (_Float16)xs[(half * 64 + j8 * 8 + m) * 132 + t];
    *(f16x8*)(r16 + j8 * 8) = H;
  }
}

// ---- main: candidates (x12 measurement reps) ----
#define EBUF_BYTES 65536
#define EH2S_OFF   65536
#define MAIN_SMEM  66560

__global__ __launch_bounds__(512, 4)
void vq_main(const _Float16* __restrict__ xth, const _Float16* __restrict__ ehg,
             const float* __restrict__ eh2g, int* __restrict__ kcnd_g) {
  __shared__ __align__(16) char smem[MAIN_SMEM];
  float* eh2s = (float*)(smem + EH2S_OFF);

  const int tid = threadIdx.x;
  const int lane = tid & 63;
  const int w = tid >> 6;
  const int hf = lane >> 5;
  const int c32 = lane & 31;
  const int q = blockIdx.x & 3;
  const int pt_base = (blockIdx.x >> 2) << 8;

  const int swz = (c32 & 15) << 4;
  const int rbase = c32 * 256 + hf * 16;

#define LOADH(dst, c, h)                                                     \
  {                                                                          \
    const int rb_ = (c) * 8192 + rbase;                                      \
    dst##0 = *(const f16x8*)(smem + ((rb_ + ((h)*4 + 0) * 32) ^ swz));       \
    dst##1 = *(const f16x8*)(smem + ((rb_ + ((h)*4 + 1) * 32) ^ swz));       \
    dst##2 = *(const f16x8*)(smem + ((rb_ + ((h)*4 + 2) * 32) ^ swz));       \
    dst##3 = *(const f16x8*)(smem + ((rb_ + ((h)*4 + 3) * 32) ^ swz));       \
  }

#pragma unroll 1
  for (int rep = 0; rep < NREP; ++rep) {
    __syncthreads();   // protect LDS reuse across reps

    // stage quarter (64 KB, inverse-swizzled src) + eh2 slice (1 KB)
    {
      const char* gq = (const char*)ehg + (size_t)q * EBUF_BYTES;
#pragma unroll
      for (int r = 0; r < 8; ++r) {
        int o = r * 8192 + tid * 16;
        int s = o ^ (((o >> 8) & 15) << 4);
        glds16(gq + s, smem + o);
      }
      if (tid < 64)
        glds16((const char*)eh2g + q * 1024 + tid * 16, smem + EH2S_OFF + tid * 16);
    }

    // x fragments: 8 contiguous 16B loads from xth row
    f16x8 xh[8];
    {
      const _Float16* xr = xth + (size_t)(pt_base + w * 32 + c32) * 128 + hf * 8;
#pragma unroll
      for (int ds = 0; ds < 8; ++ds) xh[ds] = *(const f16x8*)(xr + ds * 16);
    }
#pragma unroll
    for (int i = 0; i < 8; ++i) asm volatile("" : "+v"(xh[i]));

    __syncthreads();   // drains vmcnt: ebuf + eh2 staged

    float v1 = __uint_as_float(0xFF800000u), v2 = v1;   // -inf

    f16x8 R0_0, R0_1, R0_2, R0_3;
    f16x8 R1_0, R1_1, R1_2, R1_3;
    LOADH(R0_, 0, 0);

#pragma unroll
    for (int c = 0; c < 8; ++c) {
      const int kbl = c * 32;
      f32x16 accA, accB;
#pragma unroll
      for (int qq = 0; qq < 4; ++qq) {
        float4 v = *(const float4*)&eh2s[kbl + 4 * hf + 8 * qq];
        accA[4*qq+0] = v.x; accA[4*qq+1] = v.y;
        accA[4*qq+2] = v.z; accA[4*qq+3] = v.w;
        accB[4*qq+0] = 0.f; accB[4*qq+1] = 0.f;
        accB[4*qq+2] = 0.f; accB[4*qq+3] = 0.f;
      }
      LOADH(R1_, c, 1);
      accA = __builtin_amdgcn_mfma_f32_32x32x16_f16(R0_0, xh[0], accA, 0, 0, 0);
      accA = __builtin_amdgcn_mfma_f32_32x32x16_f16(R0_1, xh[1], accA, 0, 0, 0);
      accA = __builtin_amdgcn_mfma_f32_32x32x16_f16(R0_2, xh[2], accA, 0, 0, 0);
      accA = __builtin_amdgcn_mfma_f32_32x32x16_f16(R0_3, xh[3], accA, 0, 0, 0);
      if (c < 7) LOADH(R0_, c + 1, 0);
      accB = __builtin_amdgcn_mfma_f32_32x32x16_f16(R1_0, xh[4], accB, 0, 0, 0);
      accB = __builtin_amdgcn_mfma_f32_32x32x16_f16(R1_1, xh[5], accB, 0, 0, 0);
      accB = __builtin_amdgcn_mfma_f32_32x32x16_f16(R1_2, xh[6], accB, 0, 0, 0);
      accB = __builtin_amdgcn_mfma_f32_32x32x16_f16(R1_3, xh[7], accB, 0, 0, 0);
      const int tb = 1023 - (q * 256 + kbl) - 4 * hf;
#pragma unroll
      for (int r = 0; r < 16; r += 2) {
        float s0 = accA[r] + accB[r];
        float s1 = accA[r + 1] + accB[r + 1];
        unsigned pc0 = (unsigned)(tb - ((r & 3) + 8 * (r >> 2)));
        unsigned pc1 = (unsigned)(tb - (((r + 1) & 3) + 8 * (r >> 2)));
        float p0 = __uint_as_float((__float_as_uint(s0) & 0xFFFFFC00u) | pc0);
        float p1 = __uint_as_float((__float_as_uint(s1) & 0xFFFFFC00u) | pc1);
        float hi = fmaxf(p0, p1), lo = fminf(p0, p1);
        float nv1 = fmaxf(v1, hi);
        v2 = fmaxf(fminf(v1, hi), fmaxf(v2, lo));
        v1 = nv1;
      }
    }

    // merge hf halves -> per-point top-2 of this quarter; write packed
    {
      float m1 = __shfl_xor(v1, 32, 64);
      float m2 = __shfl_xor(v2, 32, 64);
      float c1 = fmaxf(v1, m1);
      float c2 = fmaxf(fminf(v1, m1), fmaxf(v2, m2));
      if (hf == 0) {
        int k1 = 1023 - (int)(__float_as_uint(c1) & 1023u);
        int k2 = 1023 - (int)(__float_as_uint(c2) & 1023u);
        kcnd_g[q * 32768 + pt_base + w * 32 + c32] = k1 | (k2 << 16);
      }
    }
    asm volatile("" ::: "memory");
  }
#undef LOADH
}

// ---- fin: exact rescore + gather + store + loss (x12 measurement reps) ----
#define QT_OFF   0
#define SCS_OFF  16384
#define KCS_OFF  17408
#define KFIN_OFF 18432
#define WSUM_OFF 18560
#define FIN_SMEM 18576

__global__ __launch_bounds__(256, 4)
void vq_fin(const float* __restrict__ xt32, const float* __restrict__ emb,
            const float* __restrict__ eh2g, const int* __restrict__ kcnd_g,
            float* __restrict__ out, float* __restrict__ partial) {
  __shared__ __align__(16) char smem[FIN_SMEM];
  float* scs = (float*)(smem + SCS_OFF);
  int*   kcs = (int*)(smem + KCS_OFF);
  int*   kfin = (int*)(smem + KFIN_OFF);
  float* wsum = (float*)(smem + WSUM_OFF);

  const int tid = threadIdx.x;
  const int lane = tid & 63;
  const int n0 = blockIdx.x << 5;
  const int b = n0 >> 11, t0 = n0 & 2047;
  const int team = tid >> 2, tl = tid & 3;

#pragma unroll 1
  for (int rep = 0; rep < NREP; ++rep) {
    __syncthreads();   // protect LDS reuse across reps

#pragma unroll
    for (int it = 0; it < 4; ++it) {
      const int task = it * 64 + team;
      const int p = task & 31, cand = task >> 5;
      int pk = kcnd_g[(cand >> 1) * 32768 + n0 + p];
      int kc = (pk >> (16 * (cand & 1))) & 0xFFFF;
      const float* xr = xt32 + (size_t)(n0 + p) * 128 + tl * 4;
      const float* er = emb + (size_t)kc * 128 + tl * 4;
      float dsum = 0.f;
#pragma unroll
      for (int i = 0; i < 8; ++i) {
        float4 xv = *(const float4*)(xr + i * 16);
        float4 ev = *(const float4*)(er + i * 16);
        dsum = fmaf(xv.x, ev.x, dsum); dsum = fmaf(xv.y, ev.y, dsum);
        dsum = fmaf(xv.z, ev.z, dsum); dsum = fmaf(xv.w, ev.w, dsum);
      }
      dsum += __shfl_xor(dsum, 1, 64);
      dsum += __shfl_xor(dsum, 2, 64);
      if (tl == 0) {
        scs[cand * 32 + p] = dsum + eh2g[kc];
        kcs[cand * 32 + p] = kc;
      }
    }
    __syncthreads();
    if (tid < 32) {
      float bs = scs[tid]; int bk = kcs[tid];
#pragma unroll
      for (int cd = 1; cd < 8; ++cd) {
        float v = scs[cd * 32 + tid];
        int k = kcs[cd * 32 + tid];
        if (v > bs || (v == bs && k < bk)) { bs = v; bk = k; }
      }
      kfin[tid] = bk;
    }
    __syncthreads();

    // E1: gather emb rows -> qt (slot-XOR swizzled)
    {
      const int p2 = tid >> 3, seg = tid & 7;
      const float* er2 = emb + (size_t)kfin[p2] * 128 + seg * 16;
#pragma unroll
      for (int j = 0; j < 4; ++j) {
        int slot = seg * 4 + j;
        int sw = slot ^ (p2 & 31);
        *(float4*)(smem + QT_OFF + p2 * 512 + sw * 16) = *(const float4*)&er2[j * 4];
      }
    }
    __syncthreads();

    // E2: store + loss
    float lsum = 0.f;
    {
      const int p = tid & 31, dseg = tid >> 5;
      const float* xrow = xt32 + (size_t)(n0 + p) * 128;
      float* og = out + (size_t)b * 262144 + t0 + p;
#pragma unroll
      for (int i = 0; i < 4; ++i) {
        int slot = dseg * 4 + i;
        int sw = slot ^ (p & 31);
        float4 q4 = *(const float4*)(smem + QT_OFF + p * 512 + sw * 16);
        float4 x4 = *(const float4*)(xrow + slot * 4);
        float d0 = q4.x - x4.x, d1 = q4.y - x4.y;
        float d2 = q4.z - x4.z, d3 = q4.w - x4.w;
        lsum = fmaf(d0, d0, lsum); lsum = fmaf(d1, d1, lsum);
        lsum = fmaf(d2, d2, lsum); lsum = fmaf(d3, d3, lsum);
        og[(size_t)(slot * 4 + 0) * 2048] = q4.x;
        og[(size_t)(slot * 4 + 1) * 2048] = q4.y;
        og[(size_t)(slot * 4 + 2) * 2048] = q4.z;
        og[(size_t)(slot * 4 + 3) * 2048] = q4.w;
      }
    }
#pragma unroll
    for (int off = 32; off; off >>= 1) lsum += __shfl_down(lsum, off, 64);
    if (lane == 0) wsum[tid >> 6] = lsum;
    __syncthreads();
    if (tid == 0) partial[blockIdx.x] = (wsum[0] + wsum[1]) + (wsum[2] + wsum[3]);
    asm volatile("" ::: "memory");
  }
}

__global__ void vq_loss(const float* __restrict__ partial, float* __restrict__ out) {
  int lane = threadIdx.x;  // 64 threads, 1024 partials
  float s = 0.f;
#pragma unroll
  for (int i = 0; i < 16; ++i) s += partial[i * 64 + lane];
#pragma unroll
  for (int off = 32; off; off >>= 1) s += __shfl_down(s, off, 64);
  if (lane == 0) out[4194304] = 1.25f * s / 4194304.0f;
}

extern "C" void kernel_launch(void* const* d_in, const int* in_sizes, int n_in,
                              void* d_out, int out_size, void* d_ws, size_t ws_size,
                              hipStream_t stream) {
  const float* x   = (const float*)d_in[0];   // [16,1,128,2048]
  const float* emb = (const float*)d_in[1];   // [1024,128]
  float* out = (float*)d_out;
  char* ws = (char*)d_ws;
  float*    xt32 = (float*)ws;                           // 16 MB
  _Float16* xth  = (_Float16*)(ws + 16777216);           // 8 MB
  _Float16* ehg  = (_Float16*)(ws + 25165824);           // 256 KB
  float*    eh2g = (float*)(ws + 25427968);              // 4 KB
  int*      kcnd = (int*)(ws + 25432064);                // 512 KB
  float*    partial = (float*)(ws + 25956352);           // 4 KB
  vq_prep<<<64, 256, 0, stream>>>(emb, ehg, eh2g);
  vq_prepx<<<256, 256, 0, stream>>>(x, xt32, xth);
  vq_main<<<512, 512, 0, stream>>>(xth, ehg, eh2g, kcnd);
  vq_fin<<<1024, 256, 0, stream>>>(xt32, emb, eh2g, kcnd, out, partial);
  vq_loss<<<1, 64, 0, stream>>>(partial, out);
}

// Round 12
// 59.649 us; speedup vs baseline: 6.4752x; 6.4752x over previous
//
#include <hip/hip_runtime.h>
#include <math.h>
#include <float.h>

// VQ-VAE quantizer, round 12. Two changes vs round 10 (informed by the
// round-11 amplified measurement: vq_main=26.5us and 51MB/rep cache-fill
// bound; vq_fin=2.4us; ~27us launch gaps):
//  1. vq_main block mapping q=blk>>7, pt=blk&127: blocks 128 apart share an
//     XCD (128%8==0), so a point-tile's 4 quarter-passes reuse one L2 copy
//     of xth (8MB not 32MB) and consecutive blocks reuse the L2-resident
//     ehg quarter. Attacks the measured 51MB/rep FETCH directly.
//  2. vq_prep merged into vq_prepx (one fewer launch gap).
// All math identical: score = xh.eh_k - |e|^2/2 (1 fp16 MFMA/K-step), packed
// top-2 per quarter, exact fp32 rescore of 8 candidates (verified hedge).

typedef __attribute__((ext_vector_type(8))) _Float16 f16x8;
typedef __attribute__((ext_vector_type(16))) float f32x16;

typedef __attribute__((address_space(1))) const void gas_t;
typedef __attribute__((address_space(3))) void las_t;
__device__ __forceinline__ void glds16(const void* g, void* l) {
  __builtin_amdgcn_global_load_lds((gas_t*)g, (las_t*)l, 16, 0, 0);
}

// ---- prepx (+ merged emb prep on blocks <64) ----
__global__ __launch_bounds__(256)
void vq_prepx(const float* __restrict__ x, const float* __restrict__ emb,
              float* __restrict__ xt32, _Float16* __restrict__ xth,
              _Float16* __restrict__ ehg, float* __restrict__ eh2g) {
  __shared__ float xs[128 * 132];
  const int tid = threadIdx.x;

  // merged emb prep: emb f32 -> eh fp16 + eh2 = -0.5*|e|^2 (blocks 0..63)
  if (blockIdx.x < 64) {
    const int r = blockIdx.x * 16 + (tid >> 4);
    const int seg = tid & 15;
    const float* row = emb + (size_t)r * 128 + seg * 8;
    float4 f0 = *(const float4*)&row[0];
    float4 f1 = *(const float4*)&row[4];
    float fv[8] = {f0.x, f0.y, f0.z, f0.w, f1.x, f1.y, f1.z, f1.w};
    f16x8 H;
    float ssq = 0.f;
#pragma unroll
    for (int j = 0; j < 8; ++j) {
      float f = fv[j];
      ssq = fmaf(f, f, ssq);
      H[j] = (_Float16)f;
    }
    *(f16x8*)(ehg + (size_t)r * 128 + seg * 8) = H;
#pragma unroll
    for (int off = 1; off < 16; off <<= 1) ssq += __shfl_xor(ssq, off, 64);
    if (seg == 0) eh2g[r] = -0.5f * ssq;
  }

  // x transpose tile: [B,D,T] f32 -> xt32 [N][128] f32 + xth fp16
  const int b = blockIdx.x >> 4;
  const int tt0 = (blockIdx.x & 15) << 7;
  const float* xp = x + (size_t)b * 262144 + tt0;
  for (int i = tid * 4; i < 16384; i += 1024) {
    int dd = i >> 7, tt = i & 127;
    *(float4*)&xs[dd * 132 + tt] = *(const float4*)&xp[(size_t)dd * 2048 + tt];
  }
  __syncthreads();
  const int t = tid >> 1, half = tid & 1;
  const size_t n = (size_t)b * 2048 + tt0 + t;
  float* r32 = xt32 + n * 128 + half * 64;
  _Float16* r16 = xth + n * 128 + half * 64;
#pragma unroll
  for (int j4 = 0; j4 < 16; ++j4) {
    float4 v;
    v.x = xs[(half * 64 + j4 * 4 + 0) * 132 + t];
    v.y = xs[(half * 64 + j4 * 4 + 1) * 132 + t];
    v.z = xs[(half * 64 + j4 * 4 + 2) * 132 + t];
    v.w = xs[(half * 64 + j4 * 4 + 3) * 132 + t];
    *(float4*)(r32 + j4 * 4) = v;
  }
#pragma unroll
  for (int j8 = 0; j8 < 8; ++j8) {
    f16x8 H;
#pragma unroll
    for (int m = 0; m < 8; ++m)
      H[m] = (_Float16)xs[(half * 64 + j8 * 8 + m) * 132 + t];
    *(f16x8*)(r16 + j8 * 8) = H;
  }
}

// ---- main: candidates, quarter in LDS, XCD-aligned block mapping ----
#define EBUF_BYTES 65536
#define EH2S_OFF   65536
#define MAIN_SMEM  66560

__global__ __launch_bounds__(512, 4)
void vq_main(const _Float16* __restrict__ xth, const _Float16* __restrict__ ehg,
             const float* __restrict__ eh2g, int* __restrict__ kcnd_g) {
  __shared__ __align__(16) char smem[MAIN_SMEM];
  float* eh2s = (float*)(smem + EH2S_OFF);

  const int tid = threadIdx.x;
  const int lane = tid & 63;
  const int w = tid >> 6;
  const int hf = lane >> 5;
  const int c32 = lane & 31;
  // XCD-aligned: quarter is the SLOW index; blocks 128 apart share an XCD
  // (128 % 8 == 0) -> one L2 copy of each xth tile serves all 4 quarters.
  const int q = blockIdx.x >> 7;                // codebook quarter 0..3
  const int pt_base = (blockIdx.x & 127) << 8;  // 256-pt tile

  // stage quarter (64 KB, inverse-swizzled src) + eh2 slice (1 KB)
  {
    const char* gq = (const char*)ehg + (size_t)q * EBUF_BYTES;
#pragma unroll
    for (int r = 0; r < 8; ++r) {
      int o = r * 8192 + tid * 16;
      int s = o ^ (((o >> 8) & 15) << 4);
      glds16(gq + s, smem + o);
    }
    if (tid < 64)
      glds16((const char*)eh2g + q * 1024 + tid * 16, smem + EH2S_OFF + tid * 16);
  }

  // x fragments: 8 contiguous 16B loads from xth row
  f16x8 xh[8];
  {
    const _Float16* xr = xth + (size_t)(pt_base + w * 32 + c32) * 128 + hf * 8;
#pragma unroll
    for (int ds = 0; ds < 8; ++ds) xh[ds] = *(const f16x8*)(xr + ds * 16);
  }
#pragma unroll
  for (int i = 0; i < 8; ++i) asm volatile("" : "+v"(xh[i]));  // one-time pin

  __syncthreads();   // drains vmcnt: ebuf + eh2 staged

  const int swz = (c32 & 15) << 4;
  const int rbase = c32 * 256 + hf * 16;

#define LOADH(dst, c, h)                                                     \
  {                                                                          \
    const int rb_ = (c) * 8192 + rbase;                                      \
    dst##0 = *(const f16x8*)(smem + ((rb_ + ((h)*4 + 0) * 32) ^ swz));       \
    dst##1 = *(const f16x8*)(smem + ((rb_ + ((h)*4 + 1) * 32) ^ swz));       \
    dst##2 = *(const f16x8*)(smem + ((rb_ + ((h)*4 + 2) * 32) ^ swz));       \
    dst##3 = *(const f16x8*)(smem + ((rb_ + ((h)*4 + 3) * 32) ^ swz));       \
  }

  float v1 = __uint_as_float(0xFF800000u), v2 = v1;   // -inf

  f16x8 R0_0, R0_1, R0_2, R0_3;
  f16x8 R1_0, R1_1, R1_2, R1_3;
  LOADH(R0_, 0, 0);

#pragma unroll
  for (int c = 0; c < 8; ++c) {
    const int kbl = c * 32;
    f32x16 accA, accB;
#pragma unroll
    for (int qq = 0; qq < 4; ++qq) {
      float4 v = *(const float4*)&eh2s[kbl + 4 * hf + 8 * qq];
      accA[4*qq+0] = v.x; accA[4*qq+1] = v.y;
      accA[4*qq+2] = v.z; accA[4*qq+3] = v.w;
      accB[4*qq+0] = 0.f; accB[4*qq+1] = 0.f;
      accB[4*qq+2] = 0.f; accB[4*qq+3] = 0.f;
    }
    LOADH(R1_, c, 1);
    accA = __builtin_amdgcn_mfma_f32_32x32x16_f16(R0_0, xh[0], accA, 0, 0, 0);
    accA = __builtin_amdgcn_mfma_f32_32x32x16_f16(R0_1, xh[1], accA, 0, 0, 0);
    accA = __builtin_amdgcn_mfma_f32_32x32x16_f16(R0_2, xh[2], accA, 0, 0, 0);
    accA = __builtin_amdgcn_mfma_f32_32x32x16_f16(R0_3, xh[3], accA, 0, 0, 0);
    if (c < 7) LOADH(R0_, c + 1, 0);
    accB = __builtin_amdgcn_mfma_f32_32x32x16_f16(R1_0, xh[4], accB, 0, 0, 0);
    accB = __builtin_amdgcn_mfma_f32_32x32x16_f16(R1_1, xh[5], accB, 0, 0, 0);
    accB = __builtin_amdgcn_mfma_f32_32x32x16_f16(R1_2, xh[6], accB, 0, 0, 0);
    accB = __builtin_amdgcn_mfma_f32_32x32x16_f16(R1_3, xh[7], accB, 0, 0, 0);
    const int tb = 1023 - (q * 256 + kbl) - 4 * hf;
#pragma unroll
    for (int r = 0; r < 16; r += 2) {
      float s0 = accA[r] + accB[r];
      float s1 = accA[r + 1] + accB[r + 1];
      unsigned pc0 = (unsigned)(tb - ((r & 3) + 8 * (r >> 2)));
      unsigned pc1 = (unsigned)(tb - (((r + 1) & 3) + 8 * (r >> 2)));
      float p0 = __uint_as_float((__float_as_uint(s0) & 0xFFFFFC00u) | pc0);
      float p1 = __uint_as_float((__float_as_uint(s1) & 0xFFFFFC00u) | pc1);
      float hi = fmaxf(p0, p1), lo = fminf(p0, p1);
      float nv1 = fmaxf(v1, hi);
      v2 = fmaxf(fminf(v1, hi), fmaxf(v2, lo));
      v1 = nv1;
    }
  }
#undef LOADH

  {
    float m1 = __shfl_xor(v1, 32, 64);
    float m2 = __shfl_xor(v2, 32, 64);
    float c1 = fmaxf(v1, m1);
    float c2 = fmaxf(fminf(v1, m1), fmaxf(v2, m2));
    if (hf == 0) {
      int k1 = 1023 - (int)(__float_as_uint(c1) & 1023u);
      int k2 = 1023 - (int)(__float_as_uint(c2) & 1023u);
      kcnd_g[q * 32768 + pt_base + w * 32 + c32] = k1 | (k2 << 16);
    }
  }
}

// ---- fin: exact rescore via 4-lane teams, gather, store, loss ----
#define QT_OFF   0
#define SCS_OFF  16384
#define KCS_OFF  17408
#define KFIN_OFF 18432
#define WSUM_OFF 18560
#define FIN_SMEM 18576

__global__ __launch_bounds__(256, 4)
void vq_fin(const float* __restrict__ xt32, const float* __restrict__ emb,
            const float* __restrict__ eh2g, const int* __restrict__ kcnd_g,
            float* __restrict__ out, float* __restrict__ partial) {
  __shared__ __align__(16) char smem[FIN_SMEM];
  float* scs = (float*)(smem + SCS_OFF);
  int*   kcs = (int*)(smem + KCS_OFF);
  int*   kfin = (int*)(smem + KFIN_OFF);
  float* wsum = (float*)(smem + WSUM_OFF);

  const int tid = threadIdx.x;
  const int lane = tid & 63;
  const int n0 = blockIdx.x << 5;
  const int b = n0 >> 11, t0 = n0 & 2047;
  const int team = tid >> 2, tl = tid & 3;

#pragma unroll
  for (int it = 0; it < 4; ++it) {
    const int task = it * 64 + team;
    const int p = task & 31, cand = task >> 5;
    int pk = kcnd_g[(cand >> 1) * 32768 + n0 + p];
    int kc = (pk >> (16 * (cand & 1))) & 0xFFFF;
    const float* xr = xt32 + (size_t)(n0 + p) * 128 + tl * 4;
    const float* er = emb + (size_t)kc * 128 + tl * 4;
    float dsum = 0.f;
#pragma unroll
    for (int i = 0; i < 8; ++i) {
      float4 xv = *(const float4*)(xr + i * 16);
      float4 ev = *(const float4*)(er + i * 16);
      dsum = fmaf(xv.x, ev.x, dsum); dsum = fmaf(xv.y, ev.y, dsum);
      dsum = fmaf(xv.z, ev.z, dsum); dsum = fmaf(xv.w, ev.w, dsum);
    }
    dsum += __shfl_xor(dsum, 1, 64);
    dsum += __shfl_xor(dsum, 2, 64);
    if (tl == 0) {
      scs[cand * 32 + p] = dsum + eh2g[kc];
      kcs[cand * 32 + p] = kc;
    }
  }
  __syncthreads();
  if (tid < 32) {
    float bs = scs[tid]; int bk = kcs[tid];
#pragma unroll
    for (int cd = 1; cd < 8; ++cd) {
      float v = scs[cd * 32 + tid];
      int k = kcs[cd * 32 + tid];
      if (v > bs || (v == bs && k < bk)) { bs = v; bk = k; }
    }
    kfin[tid] = bk;
  }
  __syncthreads();

  {
    const int p2 = tid >> 3, seg = tid & 7;
    const float* er2 = emb + (size_t)kfin[p2] * 128 + seg * 16;
#pragma unroll
    for (int j = 0; j < 4; ++j) {
      int slot = seg * 4 + j;
      int sw = slot ^ (p2 & 31);
      *(float4*)(smem + QT_OFF + p2 * 512 + sw * 16) = *(const float4*)&er2[j * 4];
    }
  }
  __syncthreads();

  float lsum = 0.f;
  {
    const int p = tid & 31, dseg = tid >> 5;
    const float* xrow = xt32 + (size_t)(n0 + p) * 128;
    float* og = out + (size_t)b * 262144 + t0 + p;
#pragma unroll
    for (int i = 0; i < 4; ++i) {
      int slot = dseg * 4 + i;
      int sw = slot ^ (p & 31);
      float4 q4 = *(const float4*)(smem + QT_OFF + p * 512 + sw * 16);
      float4 x4 = *(const float4*)(xrow + slot * 4);
      float d0 = q4.x - x4.x, d1 = q4.y - x4.y;
      float d2 = q4.z - x4.z, d3 = q4.w - x4.w;
      lsum = fmaf(d0, d0, lsum); lsum = fmaf(d1, d1, lsum);
      lsum = fmaf(d2, d2, lsum); lsum = fmaf(d3, d3, lsum);
      og[(size_t)(slot * 4 + 0) * 2048] = q4.x;
      og[(size_t)(slot * 4 + 1) * 2048] = q4.y;
      og[(size_t)(slot * 4 + 2) * 2048] = q4.z;
      og[(size_t)(slot * 4 + 3) * 2048] = q4.w;
    }
  }
#pragma unroll
  for (int off = 32; off; off >>= 1) lsum += __shfl_down(lsum, off, 64);
  if (lane == 0) wsum[tid >> 6] = lsum;
  __syncthreads();
  if (tid == 0) partial[blockIdx.x] = (wsum[0] + wsum[1]) + (wsum[2] + wsum[3]);
}

__global__ void vq_loss(const float* __restrict__ partial, float* __restrict__ out) {
  int lane = threadIdx.x;  // 64 threads, 1024 partials
  float s = 0.f;
#pragma unroll
  for (int i = 0; i < 16; ++i) s += partial[i * 64 + lane];
#pragma unroll
  for (int off = 32; off; off >>= 1) s += __shfl_down(s, off, 64);
  if (lane == 0) out[4194304] = 1.25f * s / 4194304.0f;
}

extern "C" void kernel_launch(void* const* d_in, const int* in_sizes, int n_in,
                              void* d_out, int out_size, void* d_ws, size_t ws_size,
                              hipStream_t stream) {
  const float* x   = (const float*)d_in[0];   // [16,1,128,2048]
  const float* emb = (const float*)d_in[1];   // [1024,128]
  float* out = (float*)d_out;
  char* ws = (char*)d_ws;
  float*    xt32 = (float*)ws;                           // 16 MB
  _Float16* xth  = (_Float16*)(ws + 16777216);           // 8 MB
  _Float16* ehg  = (_Float16*)(ws + 25165824);           // 256 KB
  float*    eh2g = (float*)(ws + 25427968);              // 4 KB
  int*      kcnd = (int*)(ws + 25432064);                // 512 KB
  float*    partial = (float*)(ws + 25956352);           // 4 KB
  vq_prepx<<<256, 256, 0, stream>>>(x, emb, xt32, xth, ehg, eh2g);
  vq_main<<<512, 512, 0, stream>>>(xth, ehg, eh2g, kcnd);
  vq_fin<<<1024, 256, 0, stream>>>(xt32, emb, eh2g, kcnd, out, partial);
  vq_loss<<<1, 64, 0, stream>>>(partial, out);
}